// Round 1
// baseline (554.907 us; speedup 1.0000x reference)
//
#include <hip/hip_runtime.h>
#include <cstdint>
#include <cstddef>
#include <math.h>

// CompactCausalAttention: B=4, T=2048, D_IN=D_OUT=1024, fp32 in/out.
// Plan: bf16 MFMA everywhere (threshold allows bf16).
//   ws layout (70MB total):
//     Xb  bf16 [8192][1024]          @ 0        (16777216 B)
//     Wt  bf16 [3][1024][1024] (W^T) @ 16777216 (6291456 B)
//     Q   bf16 [8192][1024]          @ 23068672
//     K   bf16 [8192][1024]          @ 39845888
//     Vt  bf16 [4][1024][2048] (V^T) @ 56623104
// out = fp32 [4][2048][1024]

typedef __attribute__((ext_vector_type(4))) float f32x4;
typedef __attribute__((ext_vector_type(8))) short s16x8;

static __device__ __forceinline__ unsigned short f2bf(float x) {
  unsigned int u = __float_as_uint(x);
  unsigned int r = u + 0x7FFFu + ((u >> 16) & 1u);   // RNE
  return (unsigned short)(r >> 16);
}

// ---------- convert token_embed fp32 -> bf16 ----------
__global__ __launch_bounds__(256) void k_cvtX(const float* __restrict__ X,
                                              unsigned short* __restrict__ Xb) {
  size_t i = ((size_t)blockIdx.x * 256 + threadIdx.x) * 8;
  float4 a = *(const float4*)(X + i);
  float4 b = *(const float4*)(X + i + 4);
  union { unsigned short us[8]; uint4 v; } o;
  o.us[0] = f2bf(a.x); o.us[1] = f2bf(a.y); o.us[2] = f2bf(a.z); o.us[3] = f2bf(a.w);
  o.us[4] = f2bf(b.x); o.us[5] = f2bf(b.y); o.us[6] = f2bf(b.z); o.us[7] = f2bf(b.w);
  *(uint4*)(Xb + i) = o.v;
}

// ---------- convert + transpose W [k][n] fp32 -> Wt [n][k] bf16 ----------
__global__ __launch_bounds__(256) void k_cvtW(const float* __restrict__ W0,
                                              const float* __restrict__ W1,
                                              const float* __restrict__ W2,
                                              unsigned short* __restrict__ Wt) {
  const float* W = blockIdx.z == 0 ? W0 : (blockIdx.z == 1 ? W1 : W2);
  unsigned short* dst = Wt + (size_t)blockIdx.z * 1024 * 1024;
  __shared__ float tile[64][65];
  int k0 = blockIdx.x * 64, n0 = blockIdx.y * 64;
  int tr = threadIdx.x >> 4, tc = (threadIdx.x & 15) * 4;
  for (int i = 0; i < 4; ++i) {
    int r = tr + i * 16;
    float4 v = *(const float4*)(W + (size_t)(k0 + r) * 1024 + n0 + tc);
    tile[r][tc + 0] = v.x; tile[r][tc + 1] = v.y;
    tile[r][tc + 2] = v.z; tile[r][tc + 3] = v.w;
  }
  __syncthreads();
  for (int i = 0; i < 4; ++i) {
    int r = tr + i * 16;  // n-local
    ushort4 o;
    o.x = f2bf(tile[tc + 0][r]); o.y = f2bf(tile[tc + 1][r]);
    o.z = f2bf(tile[tc + 2][r]); o.w = f2bf(tile[tc + 3][r]);
    *(ushort4*)(dst + (size_t)(n0 + r) * 1024 + k0 + tc) = o;
  }
}

// ---------- C = A * B^T (both row-major [rows][1024] bf16), m97-style ----------
// z=0: Q = Xb*Wtq^T ; z=1: K = Xb*Wtk^T ; z=2: Vt = Wtv*Xb^T (output is V^T)
__global__ __launch_bounds__(256) void k_gemm(const unsigned short* __restrict__ Xb,
                                              const unsigned short* __restrict__ Wt,
                                              unsigned short* __restrict__ Qm,
                                              unsigned short* __restrict__ Km,
                                              unsigned short* __restrict__ Vt) {
  const int z = blockIdx.z;
  const unsigned short* A; const unsigned short* B;
  int mt, nt;
  if (z < 2) { A = Xb; B = Wt + (size_t)z * 1048576; mt = blockIdx.x; nt = blockIdx.y; }
  else       { A = Wt + (size_t)2 * 1048576; B = Xb; mt = blockIdx.y; nt = blockIdx.x; }
  const int m0 = mt * 128, n0 = nt * 128;
  __shared__ unsigned short As[128 * 32];
  __shared__ unsigned short Bs[128 * 32];
  const int tid = threadIdx.x, w = tid >> 6, lane = tid & 63;
  const int wm = (w >> 1) * 64, wn = (w & 1) * 64;
  const int lr = lane & 15, lq = lane >> 4;
  f32x4 acc[4][4];
  for (int a = 0; a < 4; ++a)
    for (int b2 = 0; b2 < 4; ++b2) acc[a][b2] = (f32x4){0.f, 0.f, 0.f, 0.f};
  const int segr = lane >> 2;           // row within 16-row segment
  const int segb = (lane & 3) * 16;     // byte offset within 64B row
  for (int kt = 0; kt < 32; ++kt) {
    const int k0 = kt * 32;
    __syncthreads();
    for (int c = 0; c < 2; ++c) {
      const int seg = w * 2 + c;        // wave-uniform
      const char* ga = (const char*)A + (size_t)(m0 + seg * 16 + segr) * 2048 + (size_t)k0 * 2 + segb;
      const char* gb = (const char*)B + (size_t)(n0 + seg * 16 + segr) * 2048 + (size_t)k0 * 2 + segb;
      __builtin_amdgcn_global_load_lds((const __attribute__((address_space(1))) void*)ga,
                                       (__attribute__((address_space(3))) void*)((char*)As + seg * 1024),
                                       16, 0, 0);
      __builtin_amdgcn_global_load_lds((const __attribute__((address_space(1))) void*)gb,
                                       (__attribute__((address_space(3))) void*)((char*)Bs + seg * 1024),
                                       16, 0, 0);
    }
    __syncthreads();
    s16x8 af[4], bfv[4];
    for (int f = 0; f < 4; ++f) af[f]  = *(const s16x8*)&As[(wm + f * 16 + lr) * 32 + lq * 8];
    for (int f = 0; f < 4; ++f) bfv[f] = *(const s16x8*)&Bs[(wn + f * 16 + lr) * 32 + lq * 8];
    for (int fm = 0; fm < 4; ++fm)
      for (int fn = 0; fn < 4; ++fn)
        acc[fm][fn] = __builtin_amdgcn_mfma_f32_16x16x32_bf16(af[fm], bfv[fn], acc[fm][fn], 0, 0, 0);
  }
  for (int fm = 0; fm < 4; ++fm)
    for (int fn = 0; fn < 4; ++fn)
      for (int i = 0; i < 4; ++i) {
        int row = m0 + wm + fm * 16 + lq * 4 + i;
        int col = n0 + wn + fn * 16 + lr;
        unsigned short hv = f2bf(acc[fm][fn][i]);
        if (z == 0)      Qm[(size_t)row * 1024 + col] = hv;
        else if (z == 1) Km[(size_t)row * 1024 + col] = hv;
        else             Vt[((size_t)(col >> 11) * 1024 + row) * 2048 + (col & 2047)] = hv;
      }
}

// ---------- flash-style causal attention ----------
// block = 256 thr (4 waves). Q-tile = 16 rows, KV-tile = 64.
// wave w owns output d-slice [w*256, w*256+256). Q frags in regs; K/Vt frags
// loaded directly from global (L2/LLC). S reduced across waves in LDS.
__global__ __launch_bounds__(256) void k_flash(const unsigned short* __restrict__ Qm,
                                               const unsigned short* __restrict__ Km,
                                               const unsigned short* __restrict__ Vt,
                                               float* __restrict__ out) {
  const int bx = blockIdx.x;
  const int b = bx >> 7;
  const int q0 = (127 - (bx & 127)) * 16;   // reverse order: long rows first
  const int tid = threadIdx.x, w = tid >> 6, lane = tid & 63;
  const int lr = lane & 15, lq = lane >> 4;
  const float SCALE = 0.022097086912079608f;  // 1/sqrt(2048)

  __shared__ float Sp[4][16][64];
  __shared__ unsigned short Pl[16][64];
  __shared__ float mL[16], lL[16], aL[16];
  if (tid < 16) { mL[tid] = -INFINITY; lL[tid] = 0.f; }

  s16x8 qf[8];
  {
    const unsigned short* qp = Qm + (size_t)(b * 2048 + q0 + lr) * 1024 + w * 256 + lq * 8;
    for (int f = 0; f < 8; ++f) qf[f] = *(const s16x8*)(qp + f * 32);
  }
  f32x4 acc[16];
  for (int f = 0; f < 16; ++f) acc[f] = (f32x4){0.f, 0.f, 0.f, 0.f};

  const int nt = q0 / 64 + 1;
  for (int t = 0; t < nt; ++t) {
    const int kv0 = t * 64;
    // S partial over this wave's 256-wide d-slice
    f32x4 s[4];
    for (int f = 0; f < 4; ++f) s[f] = (f32x4){0.f, 0.f, 0.f, 0.f};
    const unsigned short* kp = Km + (size_t)(b * 2048 + kv0 + lr) * 1024 + w * 256 + lq * 8;
    for (int ks = 0; ks < 8; ++ks)
      for (int fc = 0; fc < 4; ++fc) {
        s16x8 kf = *(const s16x8*)(kp + (size_t)(fc * 16) * 1024 + ks * 32);
        s[fc] = __builtin_amdgcn_mfma_f32_16x16x32_bf16(qf[ks], kf, s[fc], 0, 0, 0);
      }
    __syncthreads();                       // Sp/Pl free (prev iter consumers done)
    for (int fc = 0; fc < 4; ++fc)
      for (int i = 0; i < 4; ++i)
        Sp[w][lq * 4 + i][fc * 16 + lr] = s[fc][i];
    __syncthreads();                       // Sp ready
    {
      const int q = tid >> 4, c = tid & 15;
      const int qabs = q0 + q;
      float sv[4];
      for (int j = 0; j < 4; ++j) {
        int kvl = c + j * 16;
        float x = (Sp[0][q][kvl] + Sp[1][q][kvl] + Sp[2][q][kvl] + Sp[3][q][kvl]) * SCALE;
        if (kv0 + kvl > qabs) x = -INFINITY;
        sv[j] = x;
      }
      float tm = fmaxf(fmaxf(sv[0], sv[1]), fmaxf(sv[2], sv[3]));
      for (int off = 8; off; off >>= 1) tm = fmaxf(tm, __shfl_xor(tm, off));
      float mold = mL[q];
      float mnew = fmaxf(mold, tm);
      float al = __expf(mold - mnew);      // first tile: exp(-inf)=0
      float ps = 0.f;
      for (int j = 0; j < 4; ++j) {
        float p = __expf(sv[j] - mnew);
        ps += p;
        Pl[q][c + j * 16] = f2bf(p);
      }
      for (int off = 8; off; off >>= 1) ps += __shfl_xor(ps, off);
      if (c == 0) { aL[q] = al; mL[q] = mnew; lL[q] = lL[q] * al + ps; }
    }
    __syncthreads();                       // Pl/aL ready
    float ai[4];
    for (int i = 0; i < 4; ++i) ai[i] = aL[lq * 4 + i];
    for (int f = 0; f < 16; ++f)
      for (int i = 0; i < 4; ++i) acc[f][i] *= ai[i];
    s16x8 pf0 = *(const s16x8*)&Pl[lr][lq * 8];
    s16x8 pf1 = *(const s16x8*)&Pl[lr][32 + lq * 8];
    const unsigned short* vp = Vt + ((size_t)b * 1024 + w * 256 + lr) * 2048 + kv0 + lq * 8;
    for (int f = 0; f < 16; ++f) {
      s16x8 v0 = *(const s16x8*)(vp + (size_t)(f * 16) * 2048);
      s16x8 v1 = *(const s16x8*)(vp + (size_t)(f * 16) * 2048 + 32);
      acc[f] = __builtin_amdgcn_mfma_f32_16x16x32_bf16(pf0, v0, acc[f], 0, 0, 0);
      acc[f] = __builtin_amdgcn_mfma_f32_16x16x32_bf16(pf1, v1, acc[f], 0, 0, 0);
    }
  }
  float li[4];
  for (int i = 0; i < 4; ++i) li[i] = 1.f / lL[lq * 4 + i];
  float* op = out + (size_t)(b * 2048 + q0) * 1024 + w * 256;
  for (int f = 0; f < 16; ++f)
    for (int i = 0; i < 4; ++i)
      op[(size_t)(lq * 4 + i) * 1024 + f * 16 + lr] = acc[f][i] * li[i];
}

extern "C" void kernel_launch(void* const* d_in, const int* in_sizes, int n_in,
                              void* d_out, int out_size, void* d_ws, size_t ws_size,
                              hipStream_t stream) {
  const float* X  = (const float*)d_in[0];
  const float* W0 = (const float*)d_in[1];
  const float* W1 = (const float*)d_in[2];
  const float* W2 = (const float*)d_in[3];
  float* out = (float*)d_out;
  char* ws = (char*)d_ws;
  unsigned short* Xb = (unsigned short*)ws;                       // 16 MB
  unsigned short* Wt = (unsigned short*)(ws + (size_t)16777216);  // 6 MB
  unsigned short* Qm = (unsigned short*)(ws + (size_t)23068672);  // 16 MB
  unsigned short* Km = (unsigned short*)(ws + (size_t)39845888);  // 16 MB
  unsigned short* Vt = (unsigned short*)(ws + (size_t)56623104);  // 16 MB
  (void)in_sizes; (void)n_in; (void)out_size; (void)ws_size;

  hipLaunchKernelGGL(k_cvtX, dim3(4096), dim3(256), 0, stream, X, Xb);
  hipLaunchKernelGGL(k_cvtW, dim3(16, 16, 3), dim3(256), 0, stream, W0, W1, W2, Wt);
  hipLaunchKernelGGL(k_gemm, dim3(64, 8, 3), dim3(256), 0, stream, Xb, Wt, Qm, Km, Vt);
  hipLaunchKernelGGL(k_flash, dim3(512), dim3(256), 0, stream, Qm, Km, Vt, out);
}

// Round 2
// 253.934 us; speedup vs baseline: 2.1852x; 2.1852x over previous
//
#include <hip/hip_runtime.h>
#include <cstdint>
#include <cstddef>
#include <math.h>

// CompactCausalAttention: B=4, T=2048, D_IN=D_OUT=1024, fp32 in/out.
// bf16 MFMA everywhere. Materialized-S attention (3 GEMM-style passes).
//   ws layout (70MB):
//     Xb  bf16 [8192][1024]          @ 0        (16MB)   } dead after k_gemm
//     Wt  bf16 [3][1024][1024] (W^T) @ 16777216 (6MB)    } dead after k_gemm
//     Q   bf16 [8192][1024]          @ 23068672 (16MB)
//     K   bf16 [8192][1024]          @ 39845888 (16MB)
//     Vt  bf16 [4][1024][2048] (V^T) @ 56623104 (16MB)
//     S   bf16 [2][2048][2048]       @ 0 (overlays Xb; per 2-batch group)
// out = fp32 [4][2048][1024]

typedef __attribute__((ext_vector_type(4))) float f32x4;
typedef __attribute__((ext_vector_type(8))) short s16x8;

static __device__ __forceinline__ unsigned short f2bf(float x) {
  unsigned int u = __float_as_uint(x);
  unsigned int r = u + 0x7FFFu + ((u >> 16) & 1u);   // RNE
  return (unsigned short)(r >> 16);
}
static __device__ __forceinline__ float bf2f(unsigned short h) {
  return __uint_as_float(((unsigned int)h) << 16);
}

// ---------- convert token_embed fp32 -> bf16 ----------
__global__ __launch_bounds__(256) void k_cvtX(const float* __restrict__ X,
                                              unsigned short* __restrict__ Xb) {
  size_t i = ((size_t)blockIdx.x * 256 + threadIdx.x) * 8;
  float4 a = *(const float4*)(X + i);
  float4 b = *(const float4*)(X + i + 4);
  union { unsigned short us[8]; uint4 v; } o;
  o.us[0] = f2bf(a.x); o.us[1] = f2bf(a.y); o.us[2] = f2bf(a.z); o.us[3] = f2bf(a.w);
  o.us[4] = f2bf(b.x); o.us[5] = f2bf(b.y); o.us[6] = f2bf(b.z); o.us[7] = f2bf(b.w);
  *(uint4*)(Xb + i) = o.v;
}

// ---------- convert + transpose W [k][n] fp32 -> Wt [n][k] bf16 ----------
__global__ __launch_bounds__(256) void k_cvtW(const float* __restrict__ W0,
                                              const float* __restrict__ W1,
                                              const float* __restrict__ W2,
                                              unsigned short* __restrict__ Wt) {
  const float* W = blockIdx.z == 0 ? W0 : (blockIdx.z == 1 ? W1 : W2);
  unsigned short* dst = Wt + (size_t)blockIdx.z * 1024 * 1024;
  __shared__ float tile[64][65];
  int k0 = blockIdx.x * 64, n0 = blockIdx.y * 64;
  int tr = threadIdx.x >> 4, tc = (threadIdx.x & 15) * 4;
  for (int i = 0; i < 4; ++i) {
    int r = tr + i * 16;
    float4 v = *(const float4*)(W + (size_t)(k0 + r) * 1024 + n0 + tc);
    tile[r][tc + 0] = v.x; tile[r][tc + 1] = v.y;
    tile[r][tc + 2] = v.z; tile[r][tc + 3] = v.w;
  }
  __syncthreads();
  for (int i = 0; i < 4; ++i) {
    int r = tr + i * 16;  // n-local
    ushort4 o;
    o.x = f2bf(tile[tc + 0][r]); o.y = f2bf(tile[tc + 1][r]);
    o.z = f2bf(tile[tc + 2][r]); o.w = f2bf(tile[tc + 3][r]);
    *(ushort4*)(dst + (size_t)(n0 + r) * 1024 + k0 + tc) = o;
  }
}

// ---------- shared m97-style GEMM core: C(128x128) = A * B^T ----------
// A, B pre-offset to tile origin; LDA_B/LDB_B are row strides in BYTES.
// nkt = number of 32-wide K-steps. acc layout: [fm][fn] 16x16 frags,
// wave w owns (wm,wn) = ((w>>1)*64, (w&1)*64).
template <int LDA_B, int LDB_B>
static __device__ __forceinline__ void gemm_core(const char* __restrict__ A,
                                                 const char* __restrict__ B,
                                                 int nkt,
                                                 unsigned short* As,
                                                 unsigned short* Bs,
                                                 f32x4 (&acc)[4][4]) {
  const int tid = threadIdx.x, w = tid >> 6, lane = tid & 63;
  const int wm = (w >> 1) * 64, wn = (w & 1) * 64;
  const int lr = lane & 15, lq = lane >> 4;
  const int segr = lane >> 2;           // row within 16-row segment
  const int segb = (lane & 3) * 16;     // byte offset within 64B row
  for (int kt = 0; kt < nkt; ++kt) {
    const int k0b = kt * 64;            // bytes along k
    __syncthreads();
    for (int c = 0; c < 2; ++c) {
      const int seg = w * 2 + c;        // wave-uniform
      const char* ga = A + (size_t)(seg * 16 + segr) * LDA_B + k0b + segb;
      const char* gb = B + (size_t)(seg * 16 + segr) * LDB_B + k0b + segb;
      __builtin_amdgcn_global_load_lds((const __attribute__((address_space(1))) void*)ga,
                                       (__attribute__((address_space(3))) void*)((char*)As + seg * 1024),
                                       16, 0, 0);
      __builtin_amdgcn_global_load_lds((const __attribute__((address_space(1))) void*)gb,
                                       (__attribute__((address_space(3))) void*)((char*)Bs + seg * 1024),
                                       16, 0, 0);
    }
    __syncthreads();
    s16x8 af[4], bfv[4];
    for (int f = 0; f < 4; ++f) af[f]  = *(const s16x8*)&As[(wm + f * 16 + lr) * 32 + lq * 8];
    for (int f = 0; f < 4; ++f) bfv[f] = *(const s16x8*)&Bs[(wn + f * 16 + lr) * 32 + lq * 8];
    for (int fm = 0; fm < 4; ++fm)
      for (int fn = 0; fn < 4; ++fn)
        acc[fm][fn] = __builtin_amdgcn_mfma_f32_16x16x32_bf16(af[fm], bfv[fn], acc[fm][fn], 0, 0, 0);
  }
}

// ---------- QKV projection: z=0 Q, z=1 K, z=2 Vt (V^T) ----------
__global__ __launch_bounds__(256) void k_gemm(const unsigned short* __restrict__ Xb,
                                              const unsigned short* __restrict__ Wt,
                                              unsigned short* __restrict__ Qm,
                                              unsigned short* __restrict__ Km,
                                              unsigned short* __restrict__ Vt) {
  const int z = blockIdx.z;
  const unsigned short* A; const unsigned short* B;
  int mt, nt;
  if (z < 2) { A = Xb; B = Wt + (size_t)z * 1048576; mt = blockIdx.x; nt = blockIdx.y; }
  else       { A = Wt + (size_t)2 * 1048576; B = Xb; mt = blockIdx.y; nt = blockIdx.x; }
  const int m0 = mt * 128, n0 = nt * 128;
  __shared__ unsigned short As[128 * 32];
  __shared__ unsigned short Bs[128 * 32];
  f32x4 acc[4][4];
  for (int a = 0; a < 4; ++a)
    for (int b2 = 0; b2 < 4; ++b2) acc[a][b2] = (f32x4){0.f, 0.f, 0.f, 0.f};
  gemm_core<2048, 2048>((const char*)(A + (size_t)m0 * 1024),
                        (const char*)(B + (size_t)n0 * 1024), 32, As, Bs, acc);
  const int tid = threadIdx.x, w = tid >> 6, lane = tid & 63;
  const int wm = (w >> 1) * 64, wn = (w & 1) * 64;
  const int lr = lane & 15, lq = lane >> 4;
  for (int fm = 0; fm < 4; ++fm)
    for (int fn = 0; fn < 4; ++fn)
      for (int i = 0; i < 4; ++i) {
        int row = m0 + wm + fm * 16 + lq * 4 + i;
        int col = n0 + wn + fn * 16 + lr;
        unsigned short hv = f2bf(acc[fm][fn][i]);
        if (z == 0)      Qm[(size_t)row * 1024 + col] = hv;
        else if (z == 1) Km[(size_t)row * 1024 + col] = hv;
        else             Vt[((size_t)(col >> 11) * 1024 + row) * 2048 + (col & 2047)] = hv;
      }
}

// ---------- pass 1: S = scale * Q K^T, causal (lower-tri) tiles only ----------
__global__ __launch_bounds__(256) void k_sgemm(const unsigned short* __restrict__ Qm,
                                               const unsigned short* __restrict__ Km,
                                               unsigned short* __restrict__ S,
                                               int b0) {
  const int id = blockIdx.x;                 // 0..135 lower-tri tile pair
  int i = (int)((sqrtf(8.f * id + 1.f) - 1.f) * 0.5f);
  while ((i + 1) * (i + 2) / 2 <= id) ++i;
  while (i * (i + 1) / 2 > id) --i;
  const int j = id - i * (i + 1) / 2;
  const int gb = blockIdx.y, bb = b0 + gb;
  const int m0 = i * 128, n0 = j * 128;
  __shared__ unsigned short As[128 * 32];
  __shared__ unsigned short Bs[128 * 32];
  f32x4 acc[4][4];
  for (int a = 0; a < 4; ++a)
    for (int b2 = 0; b2 < 4; ++b2) acc[a][b2] = (f32x4){0.f, 0.f, 0.f, 0.f};
  gemm_core<2048, 2048>((const char*)(Qm + (size_t)bb * 2097152 + (size_t)m0 * 1024),
                        (const char*)(Km + (size_t)bb * 2097152 + (size_t)n0 * 1024),
                        32, As, Bs, acc);
  const float SCALE = 0.022097086912079608f;  // 1/sqrt(2048)
  const int tid = threadIdx.x, w = tid >> 6, lane = tid & 63;
  const int wm = (w >> 1) * 64, wn = (w & 1) * 64;
  const int lr = lane & 15, lq = lane >> 4;
  for (int fm = 0; fm < 4; ++fm)
    for (int fn = 0; fn < 4; ++fn)
      for (int i2 = 0; i2 < 4; ++i2) {
        int row = m0 + wm + fm * 16 + lq * 4 + i2;
        int col = n0 + wn + fn * 16 + lr;
        S[((size_t)gb * 2048 + row) * 2048 + col] = f2bf(acc[fm][fn][i2] * SCALE);
      }
}

// ---------- pass 2: in-place masked row softmax on S (one wave per row) ----------
__global__ __launch_bounds__(256) void k_softmax(unsigned short* __restrict__ S) {
  const int row = blockIdx.x * 4 + (threadIdx.x >> 6);   // 0..4095 (2 batches)
  const int q = row & 2047;
  const int lane = threadIdx.x & 63;
  unsigned short* rp = S + (size_t)row * 2048;
  float v[32];
  for (int c = 0; c < 4; ++c) {
    s16x8 x = *(const s16x8*)(rp + c * 512 + lane * 8);
    for (int jj = 0; jj < 8; ++jj) {
      int col = c * 512 + lane * 8 + jj;
      float f = bf2f((unsigned short)x[jj]);
      v[c * 8 + jj] = (col <= q) ? f : -INFINITY;
    }
  }
  float m = -INFINITY;
  for (int t = 0; t < 32; ++t) m = fmaxf(m, v[t]);
  for (int off = 32; off; off >>= 1) m = fmaxf(m, __shfl_xor(m, off));
  float s = 0.f;
  for (int t = 0; t < 32; ++t) { v[t] = __expf(v[t] - m); s += v[t]; }
  for (int off = 32; off; off >>= 1) s += __shfl_xor(s, off);
  const float inv = 1.f / s;
  for (int c = 0; c < 4; ++c) {
    union { unsigned short us[8]; uint4 u; } o;
    for (int jj = 0; jj < 8; ++jj) o.us[jj] = f2bf(v[c * 8 + jj] * inv);
    *(uint4*)(rp + c * 512 + lane * 8) = o.u;
  }
}

// ---------- pass 3: O = P V (= P * Vt^T), K-loop truncated per tile row ----------
__global__ __launch_bounds__(256) void k_pv(const unsigned short* __restrict__ P,
                                            const unsigned short* __restrict__ Vt,
                                            float* __restrict__ out, int b0) {
  const int mt = blockIdx.x, nt = blockIdx.y, gb = blockIdx.z, bb = b0 + gb;
  const int m0 = mt * 128, n0 = nt * 128;
  __shared__ unsigned short As[128 * 32];
  __shared__ unsigned short Bs[128 * 32];
  f32x4 acc[4][4];
  for (int a = 0; a < 4; ++a)
    for (int b2 = 0; b2 < 4; ++b2) acc[a][b2] = (f32x4){0.f, 0.f, 0.f, 0.f};
  gemm_core<4096, 4096>((const char*)(P + ((size_t)gb * 2048 + m0) * 2048),
                        (const char*)(Vt + ((size_t)bb * 1024 + n0) * 2048),
                        (mt + 1) * 4, As, Bs, acc);
  const int tid = threadIdx.x, w = tid >> 6, lane = tid & 63;
  const int wm = (w >> 1) * 64, wn = (w & 1) * 64;
  const int lr = lane & 15, lq = lane >> 4;
  for (int fm = 0; fm < 4; ++fm)
    for (int fn = 0; fn < 4; ++fn)
      for (int i2 = 0; i2 < 4; ++i2) {
        int row = m0 + wm + fm * 16 + lq * 4 + i2;
        int col = n0 + wn + fn * 16 + lr;
        out[((size_t)bb * 2048 + row) * 1024 + col] = acc[fm][fn][i2];
      }
}

extern "C" void kernel_launch(void* const* d_in, const int* in_sizes, int n_in,
                              void* d_out, int out_size, void* d_ws, size_t ws_size,
                              hipStream_t stream) {
  const float* X  = (const float*)d_in[0];
  const float* W0 = (const float*)d_in[1];
  const float* W1 = (const float*)d_in[2];
  const float* W2 = (const float*)d_in[3];
  float* out = (float*)d_out;
  char* ws = (char*)d_ws;
  unsigned short* Xb = (unsigned short*)ws;                       // 16 MB
  unsigned short* Wt = (unsigned short*)(ws + (size_t)16777216);  // 6 MB
  unsigned short* Qm = (unsigned short*)(ws + (size_t)23068672);  // 16 MB
  unsigned short* Km = (unsigned short*)(ws + (size_t)39845888);  // 16 MB
  unsigned short* Vt = (unsigned short*)(ws + (size_t)56623104);  // 16 MB
  unsigned short* Sb = (unsigned short*)ws;   // S overlays Xb/Wt (dead after k_gemm)
  (void)in_sizes; (void)n_in; (void)out_size; (void)ws_size;

  hipLaunchKernelGGL(k_cvtX, dim3(4096), dim3(256), 0, stream, X, Xb);
  hipLaunchKernelGGL(k_cvtW, dim3(16, 16, 3), dim3(256), 0, stream, W0, W1, W2, Wt);
  hipLaunchKernelGGL(k_gemm, dim3(64, 8, 3), dim3(256), 0, stream, Xb, Wt, Qm, Km, Vt);
  for (int g = 0; g < 4; g += 2) {
    hipLaunchKernelGGL(k_sgemm,   dim3(136, 2), dim3(256), 0, stream, Qm, Km, Sb, g);
    hipLaunchKernelGGL(k_softmax, dim3(1024),   dim3(256), 0, stream, Sb);
    hipLaunchKernelGGL(k_pv,      dim3(16, 8, 2), dim3(256), 0, stream, Sb, Vt, out, g);
  }
}

// Round 3
// 235.561 us; speedup vs baseline: 2.3557x; 1.0780x over previous
//
#include <hip/hip_runtime.h>
#include <cstdint>
#include <cstddef>
#include <math.h>

// CompactCausalAttention: B=4, T=2048, D_IN=D_OUT=1024, fp32 in/out.
// bf16 MFMA. QKV + S-GEMM use 256^2-tile counted-vmcnt phase schedule (T3+T4+T2+T5).
//   ws layout (70MB):
//     Xb  bf16 [8192][1024]          @ 0        (16MB)   } dead after k_qkv
//     Wt  bf16 [3][1024][1024] (W^T) @ 16777216 (6MB)    } dead after k_qkv
//     Q   bf16 [8192][1024]          @ 23068672 (16MB)
//     K   bf16 [8192][1024]          @ 39845888 (16MB)
//     Vt  bf16 [4][1024][2048] (V^T) @ 56623104 (16MB)
//     S   bf16 [2][2048][2048]       @ 0 (overlays Xb/Wt; per 2-batch group)

typedef __attribute__((ext_vector_type(4))) float f32x4;
typedef __attribute__((ext_vector_type(8))) short s16x8;

#define AS1(p) ((const __attribute__((address_space(1))) void*)(p))
#define AS3(p) ((__attribute__((address_space(3))) void*)(p))
#define BARRIER() asm volatile("s_barrier" ::: "memory")
#define VMCNT(n) asm volatile("s_waitcnt vmcnt(" #n ")" ::: "memory")

static __device__ __forceinline__ unsigned short f2bf(float x) {
  unsigned int u = __float_as_uint(x);
  unsigned int r = u + 0x7FFFu + ((u >> 16) & 1u);   // RNE
  return (unsigned short)(r >> 16);
}
static __device__ __forceinline__ float bf2f(unsigned short h) {
  return __uint_as_float(((unsigned int)h) << 16);
}

// ---------- convert token_embed fp32 -> bf16 ----------
__global__ __launch_bounds__(256) void k_cvtX(const float* __restrict__ X,
                                              unsigned short* __restrict__ Xb) {
  size_t i = ((size_t)blockIdx.x * 256 + threadIdx.x) * 8;
  float4 a = *(const float4*)(X + i);
  float4 b = *(const float4*)(X + i + 4);
  union { unsigned short us[8]; uint4 v; } o;
  o.us[0] = f2bf(a.x); o.us[1] = f2bf(a.y); o.us[2] = f2bf(a.z); o.us[3] = f2bf(a.w);
  o.us[4] = f2bf(b.x); o.us[5] = f2bf(b.y); o.us[6] = f2bf(b.z); o.us[7] = f2bf(b.w);
  *(uint4*)(Xb + i) = o.v;
}

// ---------- convert + transpose W [k][n] fp32 -> Wt [n][k] bf16 ----------
__global__ __launch_bounds__(256) void k_cvtW(const float* __restrict__ W0,
                                              const float* __restrict__ W1,
                                              const float* __restrict__ W2,
                                              unsigned short* __restrict__ Wt) {
  const float* W = blockIdx.z == 0 ? W0 : (blockIdx.z == 1 ? W1 : W2);
  unsigned short* dst = Wt + (size_t)blockIdx.z * 1024 * 1024;
  __shared__ float tile[64][65];
  int k0 = blockIdx.x * 64, n0 = blockIdx.y * 64;
  int tr = threadIdx.x >> 4, tc = (threadIdx.x & 15) * 4;
  for (int i = 0; i < 4; ++i) {
    int r = tr + i * 16;
    float4 v = *(const float4*)(W + (size_t)(k0 + r) * 1024 + n0 + tc);
    tile[r][tc + 0] = v.x; tile[r][tc + 1] = v.y;
    tile[r][tc + 2] = v.z; tile[r][tc + 3] = v.w;
  }
  __syncthreads();
  for (int i = 0; i < 4; ++i) {
    int r = tr + i * 16;  // n-local
    ushort4 o;
    o.x = f2bf(tile[tc + 0][r]); o.y = f2bf(tile[tc + 1][r]);
    o.z = f2bf(tile[tc + 2][r]); o.w = f2bf(tile[tc + 3][r]);
    *(ushort4*)(dst + (size_t)(n0 + r) * 1024 + k0 + tc) = o;
  }
}

// ====================== 256^2 counted-vmcnt core ======================
// 512 thr = 8 waves (2M x 4N), per-wave output 128x64, BK=64 (2 k-halves).
// LDS: A k-half regions [256][32]bf16 @ ((buf*2+h)*16384); B same @ +65536.
// Swizzle: 16B slot ^= (row>>1)&3 (conflict-free ds_read_b128); sources
// pre-swizzled so global_load_lds (linear dst) builds the swizzled image.
static __device__ __forceinline__ void stage2(const char* src, size_t ld128, char* dst) {
  __builtin_amdgcn_global_load_lds(AS1(src), AS3(dst), 16, 0, 0);
  __builtin_amdgcn_global_load_lds(AS1(src + ld128), AS3(dst + 8192), 16, 0, 0);
}

static __device__ __forceinline__ void core256(const char* __restrict__ Ab,
                                               const char* __restrict__ Bb,
                                               int nkt, char* smem, f32x4 (&acc)[8][4]) {
  const int tid = threadIdx.x, w = tid >> 6, lane = tid & 63;
  const int lr = lane & 15, lq = lane >> 4;
  const int wm = (w >> 2) * 128, wn = (w & 3) * 64;
  const int rowl = w * 16 + (lane >> 2);                 // staging row (l=0)
  const int slotL = (lane & 3) ^ ((rowl >> 1) & 3);      // pre-swizzled source slot
  const size_t laneOff = (size_t)rowl * 2048 + slotL * 16;   // ld = 2048B
  const char* As = Ab + laneOff;
  const char* Bs = Bb + laneOff;
  char* ldsA = smem + w * 1024;
  char* ldsB = smem + 65536 + w * 1024;

#define STAGE_A(t, h) stage2(As + (size_t)(t) * 128 + (h) * 64, (size_t)128 * 2048, \
                             ldsA + (((t) & 1) * 2 + (h)) * 16384)
#define STAGE_B(t, h) stage2(Bs + (size_t)(t) * 128 + (h) * 64, (size_t)128 * 2048, \
                             ldsB + (((t) & 1) * 2 + (h)) * 16384)
#define RD_A(buf, h, r) (*(const s16x8*)(smem + ((buf) * 2 + (h)) * 16384 + (r) * 64 + ((lq ^ (((r) >> 1) & 3)) << 4)))
#define RD_B(buf, h, r) (*(const s16x8*)(smem + 65536 + ((buf) * 2 + (h)) * 16384 + (r) * 64 + ((lq ^ (((r) >> 1) & 3)) << 4)))

  // prologue: tile 0 fully staged; wait for its k-half 0
  STAGE_A(0, 0); STAGE_B(0, 0); STAGE_A(0, 1); STAGE_B(0, 1);
  VMCNT(4);
  BARRIER();

  s16x8 af[4], bfr[4];
  for (int t = 0; t < nkt; ++t) {
    const int buf = t & 1;
    const bool more = (t + 1) < nkt;
    // ---- phase 0: rows 0-3, k-half 0 ----
#pragma unroll
    for (int i = 0; i < 4; ++i) af[i] = RD_A(buf, 0, wm + i * 16 + lr);
#pragma unroll
    for (int c = 0; c < 4; ++c) bfr[c] = RD_B(buf, 0, wn + c * 16 + lr);
    if (more) STAGE_A(t + 1, 0);
    BARRIER();
    __builtin_amdgcn_s_setprio(1);
#pragma unroll
    for (int i = 0; i < 4; ++i)
#pragma unroll
      for (int c = 0; c < 4; ++c)
        acc[i][c] = __builtin_amdgcn_mfma_f32_16x16x32_bf16(af[i], bfr[c], acc[i][c], 0, 0, 0);
    __builtin_amdgcn_s_setprio(0);
    BARRIER();
    // ---- phase 1: rows 4-7, k-half 0 ----
#pragma unroll
    for (int i = 0; i < 4; ++i) af[i] = RD_A(buf, 0, wm + 64 + i * 16 + lr);
    if (more) STAGE_B(t + 1, 0);
    BARRIER();
    __builtin_amdgcn_s_setprio(1);
#pragma unroll
    for (int i = 0; i < 4; ++i)
#pragma unroll
      for (int c = 0; c < 4; ++c)
        acc[4 + i][c] = __builtin_amdgcn_mfma_f32_16x16x32_bf16(af[i], bfr[c], acc[4 + i][c], 0, 0, 0);
    __builtin_amdgcn_s_setprio(0);
    if (more) { VMCNT(4); } else { VMCNT(0); }   // k-half 1 of tile t arrived
    BARRIER();
    // ---- phase 2: rows 0-3, k-half 1 ----
#pragma unroll
    for (int i = 0; i < 4; ++i) af[i] = RD_A(buf, 1, wm + i * 16 + lr);
#pragma unroll
    for (int c = 0; c < 4; ++c) bfr[c] = RD_B(buf, 1, wn + c * 16 + lr);
    if (more) STAGE_A(t + 1, 1);
    BARRIER();
    __builtin_amdgcn_s_setprio(1);
#pragma unroll
    for (int i = 0; i < 4; ++i)
#pragma unroll
      for (int c = 0; c < 4; ++c)
        acc[i][c] = __builtin_amdgcn_mfma_f32_16x16x32_bf16(af[i], bfr[c], acc[i][c], 0, 0, 0);
    __builtin_amdgcn_s_setprio(0);
    BARRIER();
    // ---- phase 3: rows 4-7, k-half 1 ----
#pragma unroll
    for (int i = 0; i < 4; ++i) af[i] = RD_A(buf, 1, wm + 64 + i * 16 + lr);
    if (more) STAGE_B(t + 1, 1);
    BARRIER();
    __builtin_amdgcn_s_setprio(1);
#pragma unroll
    for (int i = 0; i < 4; ++i)
#pragma unroll
      for (int c = 0; c < 4; ++c)
        acc[4 + i][c] = __builtin_amdgcn_mfma_f32_16x16x32_bf16(af[i], bfr[c], acc[4 + i][c], 0, 0, 0);
    __builtin_amdgcn_s_setprio(0);
    if (more) { VMCNT(4); }   // next tile's k-half 0 arrived
    BARRIER();
  }
#undef STAGE_A
#undef STAGE_B
#undef RD_A
#undef RD_B
}

// ---------- QKV projection (256^2 core): y in [0,12): z=y>>2 ----------
__global__ __launch_bounds__(512, 2) void k_qkv(const unsigned short* __restrict__ Xb,
                                                const unsigned short* __restrict__ Wt,
                                                unsigned short* __restrict__ Qm,
                                                unsigned short* __restrict__ Km,
                                                unsigned short* __restrict__ Vt) {
  __shared__ char smem[131072];
  const int by = blockIdx.y, z = by >> 2, q = by & 3, bx = blockIdx.x;
  const char* A; const char* B;
  int m0, n0;
  if (z < 2) {
    m0 = bx * 256; n0 = q * 256;
    A = (const char*)(Xb + (size_t)m0 * 1024);
    B = (const char*)(Wt + (size_t)z * 1048576 + (size_t)n0 * 1024);
  } else {
    m0 = q * 256; n0 = bx * 256;
    A = (const char*)(Wt + (size_t)2 * 1048576 + (size_t)m0 * 1024);
    B = (const char*)(Xb + (size_t)n0 * 1024);
  }
  f32x4 acc[8][4];
#pragma unroll
  for (int i = 0; i < 8; ++i)
#pragma unroll
    for (int c = 0; c < 4; ++c) acc[i][c] = (f32x4){0.f, 0.f, 0.f, 0.f};
  core256(A, B, 16, smem, acc);
  const int tid = threadIdx.x, w = tid >> 6, lane = tid & 63;
  const int lr = lane & 15, lq = lane >> 4;
  const int wm = (w >> 2) * 128, wn = (w & 3) * 64;
#pragma unroll
  for (int fr = 0; fr < 8; ++fr)
#pragma unroll
    for (int fc = 0; fc < 4; ++fc)
#pragma unroll
      for (int i = 0; i < 4; ++i) {
        int row = m0 + wm + fr * 16 + lq * 4 + i;
        int col = n0 + wn + fc * 16 + lr;
        unsigned short hv = f2bf(acc[fr][fc][i]);
        if (z == 0)      Qm[(size_t)row * 1024 + col] = hv;
        else if (z == 1) Km[(size_t)row * 1024 + col] = hv;
        else             Vt[((size_t)(col >> 11) * 1024 + row) * 2048 + (col & 2047)] = hv;
      }
}

// ---------- pass 1: S = scale * Q K^T, causal 256^2 tiles (i>=j) ----------
__global__ __launch_bounds__(512, 2) void k_sg(const unsigned short* __restrict__ Qm,
                                               const unsigned short* __restrict__ Km,
                                               unsigned short* __restrict__ S,
                                               int b0) {
  __shared__ char smem[131072];
  const int id = blockIdx.x;   // 0..35
  int i = 0;
  while ((i + 1) * (i + 2) / 2 <= id) ++i;
  const int j = id - i * (i + 1) / 2;
  const int gb = blockIdx.y, bb = b0 + gb;
  const int m0 = i * 256, n0 = j * 256;
  f32x4 acc[8][4];
#pragma unroll
  for (int a = 0; a < 8; ++a)
#pragma unroll
    for (int c = 0; c < 4; ++c) acc[a][c] = (f32x4){0.f, 0.f, 0.f, 0.f};
  core256((const char*)(Qm + ((size_t)bb * 2048 + m0) * 1024),
          (const char*)(Km + ((size_t)bb * 2048 + n0) * 1024), 16, smem, acc);
  const float SCALE = 0.022097086912079608f;  // 1/sqrt(2048)
  const int tid = threadIdx.x, w = tid >> 6, lane = tid & 63;
  const int lr = lane & 15, lq = lane >> 4;
  const int wm = (w >> 2) * 128, wn = (w & 3) * 64;
#pragma unroll
  for (int fr = 0; fr < 8; ++fr)
#pragma unroll
    for (int fc = 0; fc < 4; ++fc)
#pragma unroll
      for (int i2 = 0; i2 < 4; ++i2) {
        int row = m0 + wm + fr * 16 + lq * 4 + i2;
        int col = n0 + wn + fc * 16 + lr;
        S[((size_t)gb * 2048 + row) * 2048 + col] = f2bf(acc[fr][fc][i2] * SCALE);
      }
}

// ---------- old 128^2 core (kept for PV: per-row truncated K) ----------
template <int LDA_B, int LDB_B>
static __device__ __forceinline__ void gemm_core(const char* __restrict__ A,
                                                 const char* __restrict__ B,
                                                 int nkt,
                                                 unsigned short* As,
                                                 unsigned short* Bs,
                                                 f32x4 (&acc)[4][4]) {
  const int tid = threadIdx.x, w = tid >> 6, lane = tid & 63;
  const int wm = (w >> 1) * 64, wn = (w & 1) * 64;
  const int lr = lane & 15, lq = lane >> 4;
  const int segr = lane >> 2;
  const int segb = (lane & 3) * 16;
  for (int kt = 0; kt < nkt; ++kt) {
    const int k0b = kt * 64;
    __syncthreads();
    for (int c = 0; c < 2; ++c) {
      const int seg = w * 2 + c;
      const char* ga = A + (size_t)(seg * 16 + segr) * LDA_B + k0b + segb;
      const char* gb = B + (size_t)(seg * 16 + segr) * LDB_B + k0b + segb;
      __builtin_amdgcn_global_load_lds(AS1(ga), AS3((char*)As + seg * 1024), 16, 0, 0);
      __builtin_amdgcn_global_load_lds(AS1(gb), AS3((char*)Bs + seg * 1024), 16, 0, 0);
    }
    __syncthreads();
    s16x8 af[4], bfv[4];
    for (int f = 0; f < 4; ++f) af[f]  = *(const s16x8*)&As[(wm + f * 16 + lr) * 32 + lq * 8];
    for (int f = 0; f < 4; ++f) bfv[f] = *(const s16x8*)&Bs[(wn + f * 16 + lr) * 32 + lq * 8];
    for (int fm = 0; fm < 4; ++fm)
      for (int fn = 0; fn < 4; ++fn)
        acc[fm][fn] = __builtin_amdgcn_mfma_f32_16x16x32_bf16(af[fm], bfv[fn], acc[fm][fn], 0, 0, 0);
  }
}

// ---------- pass 2: in-place masked row softmax on S ----------
__global__ __launch_bounds__(256) void k_softmax(unsigned short* __restrict__ S) {
  const int row = blockIdx.x * 4 + (threadIdx.x >> 6);   // 0..4095 (2 batches)
  const int q = row & 2047;
  const int lane = threadIdx.x & 63;
  unsigned short* rp = S + (size_t)row * 2048;
  float v[32];
  for (int c = 0; c < 4; ++c) {
    s16x8 x = *(const s16x8*)(rp + c * 512 + lane * 8);
    for (int jj = 0; jj < 8; ++jj) {
      int col = c * 512 + lane * 8 + jj;
      float f = bf2f((unsigned short)x[jj]);
      v[c * 8 + jj] = (col <= q) ? f : -INFINITY;
    }
  }
  float m = -INFINITY;
  for (int t = 0; t < 32; ++t) m = fmaxf(m, v[t]);
  for (int off = 32; off; off >>= 1) m = fmaxf(m, __shfl_xor(m, off));
  float s = 0.f;
  for (int t = 0; t < 32; ++t) { v[t] = __expf(v[t] - m); s += v[t]; }
  for (int off = 32; off; off >>= 1) s += __shfl_xor(s, off);
  const float inv = 1.f / s;
  for (int c = 0; c < 4; ++c) {
    union { unsigned short us[8]; uint4 u; } o;
    for (int jj = 0; jj < 8; ++jj) o.us[jj] = f2bf(v[c * 8 + jj] * inv);
    *(uint4*)(rp + c * 512 + lane * 8) = o.u;
  }
}

// ---------- pass 3: O = P V (= P * Vt^T), K-loop truncated per tile row ----------
__global__ __launch_bounds__(256) void k_pv(const unsigned short* __restrict__ P,
                                            const unsigned short* __restrict__ Vt,
                                            float* __restrict__ out, int b0) {
  const int mt = blockIdx.x, nt = blockIdx.y, gb = blockIdx.z, bb = b0 + gb;
  const int m0 = mt * 128, n0 = nt * 128;
  __shared__ unsigned short As[128 * 32];
  __shared__ unsigned short Bs[128 * 32];
  f32x4 acc[4][4];
  for (int a = 0; a < 4; ++a)
    for (int b2 = 0; b2 < 4; ++b2) acc[a][b2] = (f32x4){0.f, 0.f, 0.f, 0.f};
  gemm_core<4096, 4096>((const char*)(P + ((size_t)gb * 2048 + m0) * 2048),
                        (const char*)(Vt + ((size_t)bb * 1024 + n0) * 2048),
                        (mt + 1) * 4, As, Bs, acc);
  const int tid = threadIdx.x, w = tid >> 6, lane = tid & 63;
  const int wm = (w >> 1) * 64, wn = (w & 1) * 64;
  const int lr = lane & 15, lq = lane >> 4;
  for (int fm = 0; fm < 4; ++fm)
    for (int fn = 0; fn < 4; ++fn)
      for (int i2 = 0; i2 < 4; ++i2) {
        int row = m0 + wm + fm * 16 + lq * 4 + i2;
        int col = n0 + wn + fn * 16 + lr;
        out[((size_t)bb * 2048 + row) * 1024 + col] = acc[fm][fn][i2];
      }
}

extern "C" void kernel_launch(void* const* d_in, const int* in_sizes, int n_in,
                              void* d_out, int out_size, void* d_ws, size_t ws_size,
                              hipStream_t stream) {
  const float* X  = (const float*)d_in[0];
  const float* W0 = (const float*)d_in[1];
  const float* W1 = (const float*)d_in[2];
  const float* W2 = (const float*)d_in[3];
  float* out = (float*)d_out;
  char* ws = (char*)d_ws;
  unsigned short* Xb = (unsigned short*)ws;                       // 16 MB
  unsigned short* Wt = (unsigned short*)(ws + (size_t)16777216);  // 6 MB
  unsigned short* Qm = (unsigned short*)(ws + (size_t)23068672);  // 16 MB
  unsigned short* Km = (unsigned short*)(ws + (size_t)39845888);  // 16 MB
  unsigned short* Vt = (unsigned short*)(ws + (size_t)56623104);  // 16 MB
  unsigned short* Sb = (unsigned short*)ws;   // S overlays Xb/Wt (dead after k_qkv)
  (void)in_sizes; (void)n_in; (void)out_size; (void)ws_size;

  hipLaunchKernelGGL(k_cvtX, dim3(4096), dim3(256), 0, stream, X, Xb);
  hipLaunchKernelGGL(k_cvtW, dim3(16, 16, 3), dim3(256), 0, stream, W0, W1, W2, Wt);
  hipLaunchKernelGGL(k_qkv, dim3(32, 12), dim3(512), 0, stream, Xb, Wt, Qm, Km, Vt);
  for (int g = 0; g < 4; g += 2) {
    hipLaunchKernelGGL(k_sg,      dim3(36, 2),   dim3(512), 0, stream, Qm, Km, Sb, g);
    hipLaunchKernelGGL(k_softmax, dim3(1024),    dim3(256), 0, stream, Sb);
    hipLaunchKernelGGL(k_pv,      dim3(16, 8, 2), dim3(256), 0, stream, Sb, Vt, out, g);
  }
}

// Round 4
// 179.939 us; speedup vs baseline: 3.0839x; 1.3091x over previous
//
#include <hip/hip_runtime.h>
#include <cstdint>
#include <cstddef>
#include <math.h>

// CompactCausalAttention: B=4, T=2048, D_IN=D_OUT=1024, fp32 in/out.
// bf16 MFMA. 256^2 deep counted-vmcnt core for QKV / S / PV.
//   ws layout (70MB):
//     Xb  bf16 [8192][1024]          @ 0        (16MB)   } dead after k_qkv
//     Wt  bf16 [3][1024][1024] (W^T) @ 16777216 (6MB)    } dead after k_qkv
//     Q   bf16 [8192][1024]          @ 23068672 (16MB)
//     K   bf16 [8192][1024]          @ 39845888 (16MB)
//     Vt  bf16 [4][1024][2048] (V^T) @ 56623104 (16MB)
//     S   bf16 [4][36][256][256] packed lower-tri tiles @ 0 (18MB, overlays Xb/Wt)

typedef __attribute__((ext_vector_type(4))) float f32x4;
typedef __attribute__((ext_vector_type(8))) short s16x8;

#define AS1(p) ((const __attribute__((address_space(1))) void*)(p))
#define AS3(p) ((__attribute__((address_space(3))) void*)(p))
#define BARRIER() asm volatile("s_barrier" ::: "memory")
#define W8 asm volatile("s_waitcnt vmcnt(8)" ::: "memory")
#define W4 asm volatile("s_waitcnt vmcnt(4)" ::: "memory")
#define W0 asm volatile("s_waitcnt vmcnt(0)" ::: "memory")
#define WNONE ((void)0)
#define NOISSUE ((void)0)

static __device__ __forceinline__ unsigned short f2bf(float x) {
  unsigned int u = __float_as_uint(x);
  unsigned int r = u + 0x7FFFu + ((u >> 16) & 1u);   // RNE
  return (unsigned short)(r >> 16);
}
static __device__ __forceinline__ float bf2f(unsigned short h) {
  return __uint_as_float(((unsigned int)h) << 16);
}

// ---------- convert token_embed fp32 -> bf16 ----------
__global__ __launch_bounds__(256) void k_cvtX(const float* __restrict__ X,
                                              unsigned short* __restrict__ Xb) {
  size_t i = ((size_t)blockIdx.x * 256 + threadIdx.x) * 8;
  float4 a = *(const float4*)(X + i);
  float4 b = *(const float4*)(X + i + 4);
  union { unsigned short us[8]; uint4 v; } o;
  o.us[0] = f2bf(a.x); o.us[1] = f2bf(a.y); o.us[2] = f2bf(a.z); o.us[3] = f2bf(a.w);
  o.us[4] = f2bf(b.x); o.us[5] = f2bf(b.y); o.us[6] = f2bf(b.z); o.us[7] = f2bf(b.w);
  *(uint4*)(Xb + i) = o.v;
}

// ---------- convert + transpose W [k][n] fp32 -> Wt [n][k] bf16 ----------
__global__ __launch_bounds__(256) void k_cvtW(const float* __restrict__ W0p,
                                              const float* __restrict__ W1p,
                                              const float* __restrict__ W2p,
                                              unsigned short* __restrict__ Wt) {
  const float* W = blockIdx.z == 0 ? W0p : (blockIdx.z == 1 ? W1p : W2p);
  unsigned short* dst = Wt + (size_t)blockIdx.z * 1024 * 1024;
  __shared__ float tile[64][65];
  int k0 = blockIdx.x * 64, n0 = blockIdx.y * 64;
  int tr = threadIdx.x >> 4, tc = (threadIdx.x & 15) * 4;
  for (int i = 0; i < 4; ++i) {
    int r = tr + i * 16;
    float4 v = *(const float4*)(W + (size_t)(k0 + r) * 1024 + n0 + tc);
    tile[r][tc + 0] = v.x; tile[r][tc + 1] = v.y;
    tile[r][tc + 2] = v.z; tile[r][tc + 3] = v.w;
  }
  __syncthreads();
  for (int i = 0; i < 4; ++i) {
    int r = tr + i * 16;  // n-local
    ushort4 o;
    o.x = f2bf(tile[tc + 0][r]); o.y = f2bf(tile[tc + 1][r]);
    o.z = f2bf(tile[tc + 2][r]); o.w = f2bf(tile[tc + 3][r]);
    *(ushort4*)(dst + (size_t)(n0 + r) * 1024 + k0 + tc) = o;
  }
}

// ====================== 256^2 deep counted-vmcnt core ======================
// 512 thr = 8 waves (2M x 4N), per-wave output 128x64, BK=64 (2 k-halves).
// LDS: A k-half regions [256][32]bf16 @ ((buf*2+h)*16384); B same @ +65536.
// Swizzle: 16B slot ^= (row>>1)&3; sources pre-swizzled (linear gload_lds dst).
// Staging issued 1.5-2 tiles ahead; uniform vmcnt(8) waits (64KB in flight).
static __device__ __forceinline__ void stage2(const char* src, size_t ld128, char* dst) {
  __builtin_amdgcn_global_load_lds(AS1(src), AS3(dst), 16, 0, 0);
  __builtin_amdgcn_global_load_lds(AS1(src + ld128), AS3(dst + 8192), 16, 0, 0);
}

template <class FA, class FB>
static __device__ __forceinline__ void core256(const char* __restrict__ As,
                                               const char* __restrict__ Bs,
                                               size_t ldA128, size_t ldB128,
                                               FA offA, FB offB,
                                               int nkt, char* smem, f32x4 (&acc)[8][4]) {
  const int tid = threadIdx.x, w = tid >> 6, lane = tid & 63;
  const int lr = lane & 15, lq = lane >> 4;
  const int wm = (w >> 2) * 128, wn = (w & 3) * 64;
  char* ldsA = smem + w * 1024;
  char* ldsB = smem + 65536 + w * 1024;
  s16x8 af[4], bfr[4];

#define STG_A(t, h) stage2(As + offA((t), (h)), ldA128, ldsA + (((t) & 1) * 2 + (h)) * 16384)
#define STG_B(t, h) stage2(Bs + offB((t), (h)), ldB128, ldsB + (((t) & 1) * 2 + (h)) * 16384)
#define RD_A(buf, h, r) (*(const s16x8*)(smem + ((buf) * 2 + (h)) * 16384 + (r) * 64 + ((lq ^ (((r) >> 1) & 3)) << 4)))
#define RD_B(buf, h, r) (*(const s16x8*)(smem + 65536 + ((buf) * 2 + (h)) * 16384 + (r) * 64 + ((lq ^ (((r) >> 1) & 3)) << 4)))
#define ISS_H1(T) do { STG_A((T) + 1, 1); STG_B((T) + 1, 1); } while (0)
#define ISS_H0(T) do { STG_A((T) + 2, 0); STG_B((T) + 2, 0); } while (0)
#define MFMA_Q(base)                                                                     \
  _Pragma("unroll") for (int i = 0; i < 4; ++i)                                          \
  _Pragma("unroll") for (int c = 0; c < 4; ++c)                                          \
    acc[(base) + i][c] = __builtin_amdgcn_mfma_f32_16x16x32_bf16(af[i], bfr[c], acc[(base) + i][c], 0, 0, 0)
#define PH02(buf, h, ISSUE)                                                              \
  _Pragma("unroll") for (int i = 0; i < 4; ++i) af[i] = RD_A(buf, h, wm + i * 16 + lr);  \
  _Pragma("unroll") for (int c = 0; c < 4; ++c) bfr[c] = RD_B(buf, h, wn + c * 16 + lr); \
  ISSUE; BARRIER();                                                                      \
  __builtin_amdgcn_s_setprio(1); MFMA_Q(0); __builtin_amdgcn_s_setprio(0);               \
  BARRIER();
#define PH13(buf, h, WAIT)                                                               \
  _Pragma("unroll") for (int i = 0; i < 4; ++i) af[i] = RD_A(buf, h, wm + 64 + i * 16 + lr); \
  BARRIER();                                                                             \
  __builtin_amdgcn_s_setprio(1); MFMA_Q(4); __builtin_amdgcn_s_setprio(0);               \
  WAIT; BARRIER();
#define TILE(T, ISS0, ISS2, WAIT1, WAIT3) {                                              \
    const int _buf = (T) & 1;                                                            \
    PH02(_buf, 0, ISS0)                                                                  \
    PH13(_buf, 0, WAIT1)                                                                 \
    PH02(_buf, 1, ISS2)                                                                  \
    PH13(_buf, 1, WAIT3)                                                                 \
  }

  // prologue: (0,h0) (0,h1) (1,h0) staged; wait for (0,h0) leaving 8 in flight
  STG_A(0, 0); STG_B(0, 0);
  STG_A(0, 1); STG_B(0, 1);
  STG_A(1, 0); STG_B(1, 0);
  W8; BARRIER();

  int t = 0;
  for (; t + 2 < nkt; ++t) TILE(t, ISS_H1(t), ISS_H0(t), W8, W8)
  TILE(t, ISS_H1(t), NOISSUE, W8, W4)
  ++t;
  TILE(t, NOISSUE, NOISSUE, W0, WNONE)

#undef STG_A
#undef STG_B
#undef RD_A
#undef RD_B
#undef ISS_H1
#undef ISS_H0
#undef MFMA_Q
#undef PH02
#undef PH13
#undef TILE
}

struct OffLinear {
  __device__ __forceinline__ size_t operator()(int t, int h) const {
    return (size_t)t * 128 + (size_t)h * 64;
  }
};
struct OffTri {   // packed S tiles: 4 K-steps per 256^2 tile, tile stride 128KB
  __device__ __forceinline__ size_t operator()(int t, int h) const {
    return (size_t)(t >> 2) * 131072 + (size_t)(t & 3) * 128 + (size_t)h * 64;
  }
};

static __device__ __forceinline__ void lane_src(int ld, int& rowl, int& slot) {
  const int tid = threadIdx.x, w = tid >> 6, lane = tid & 63;
  rowl = w * 16 + (lane >> 2);
  slot = (lane & 3) ^ ((rowl >> 1) & 3);
  (void)ld;
}

// ---------- QKV projection: y in [0,12): z=y>>2 ----------
__global__ __launch_bounds__(512, 2) void k_qkv(const unsigned short* __restrict__ Xb,
                                                const unsigned short* __restrict__ Wt,
                                                unsigned short* __restrict__ Qm,
                                                unsigned short* __restrict__ Km,
                                                unsigned short* __restrict__ Vt) {
  __shared__ char smem[131072];
  const int by = blockIdx.y, z = by >> 2, q = by & 3, bx = blockIdx.x;
  const char* A; const char* B;
  int m0, n0;
  if (z < 2) {
    m0 = bx * 256; n0 = q * 256;
    A = (const char*)(Xb + (size_t)m0 * 1024);
    B = (const char*)(Wt + (size_t)z * 1048576 + (size_t)n0 * 1024);
  } else {
    m0 = q * 256; n0 = bx * 256;
    A = (const char*)(Wt + (size_t)2 * 1048576 + (size_t)m0 * 1024);
    B = (const char*)(Xb + (size_t)n0 * 1024);
  }
  int rowl, slot; lane_src(2048, rowl, slot);
  const size_t lo = (size_t)rowl * 2048 + slot * 16;
  f32x4 acc[8][4];
#pragma unroll
  for (int i = 0; i < 8; ++i)
#pragma unroll
    for (int c = 0; c < 4; ++c) acc[i][c] = (f32x4){0.f, 0.f, 0.f, 0.f};
  core256(A + lo, B + lo, (size_t)128 * 2048, (size_t)128 * 2048,
          OffLinear{}, OffLinear{}, 16, smem, acc);
  const int tid = threadIdx.x, w = tid >> 6, lane = tid & 63;
  const int lr = lane & 15, lq = lane >> 4;
  const int wm = (w >> 2) * 128, wn = (w & 3) * 64;
#pragma unroll
  for (int fr = 0; fr < 8; ++fr)
#pragma unroll
    for (int fc = 0; fc < 4; ++fc)
#pragma unroll
      for (int i = 0; i < 4; ++i) {
        int row = m0 + wm + fr * 16 + lq * 4 + i;
        int col = n0 + wn + fc * 16 + lr;
        unsigned short hv = f2bf(acc[fr][fc][i]);
        if (z == 0)      Qm[(size_t)row * 1024 + col] = hv;
        else if (z == 1) Km[(size_t)row * 1024 + col] = hv;
        else             Vt[((size_t)(col >> 11) * 1024 + row) * 2048 + (col & 2047)] = hv;
      }
}

// ---------- pass 1: packed-tri S = scale*Q K^T, all 4 batches ----------
__global__ __launch_bounds__(512, 2) void k_sg(const unsigned short* __restrict__ Qm,
                                               const unsigned short* __restrict__ Km,
                                               unsigned short* __restrict__ S) {
  __shared__ char smem[131072];
  const int id = blockIdx.x;   // 0..35 lower-tri tile
  int i = 0;
  while ((i + 1) * (i + 2) / 2 <= id) ++i;
  const int j = id - i * (i + 1) / 2;
  const int b = blockIdx.y;
  const int m0 = i * 256, n0 = j * 256;
  int rowl, slot; lane_src(2048, rowl, slot);
  const size_t lo = (size_t)rowl * 2048 + slot * 16;
  f32x4 acc[8][4];
#pragma unroll
  for (int a = 0; a < 8; ++a)
#pragma unroll
    for (int c = 0; c < 4; ++c) acc[a][c] = (f32x4){0.f, 0.f, 0.f, 0.f};
  core256((const char*)(Qm + ((size_t)b * 2048 + m0) * 1024) + lo,
          (const char*)(Km + ((size_t)b * 2048 + n0) * 1024) + lo,
          (size_t)128 * 2048, (size_t)128 * 2048, OffLinear{}, OffLinear{}, 16, smem, acc);
  const float SCALE = 0.022097086912079608f;  // 1/sqrt(2048)
  const int tid = threadIdx.x, w = tid >> 6, lane = tid & 63;
  const int lr = lane & 15, lq = lane >> 4;
  const int wm = (w >> 2) * 128, wn = (w & 3) * 64;
  unsigned short* tb = S + (((size_t)(b * 36 + id)) << 16);
#pragma unroll
  for (int fr = 0; fr < 8; ++fr)
#pragma unroll
    for (int fc = 0; fc < 4; ++fc)
#pragma unroll
      for (int i2 = 0; i2 < 4; ++i2) {
        int rl = wm + fr * 16 + lq * 4 + i2;
        int cl = wn + fc * 16 + lr;
        tb[(size_t)rl * 256 + cl] = f2bf(acc[fr][fc][i2] * SCALE);
      }
}

// ---------- pass 2: masked row softmax on packed S (one wave per row) ----------
__global__ __launch_bounds__(256) void k_softmax(unsigned short* __restrict__ S) {
  const int tid = threadIdx.x, w = tid >> 6, lane = tid & 63;
  const int row = blockIdx.x * 4 + w;       // 0..8191
  const int b = row >> 11, q = row & 2047;
  const int i = q >> 8, ntl = i + 1, rowL = q & 255;
  unsigned short* base = S + (((size_t)(b * 36 + (i * (i + 1)) / 2)) << 16)
                           + (size_t)rowL * 256 + lane * 4;
  float v[8][4];
#pragma unroll
  for (int t = 0; t < 8; ++t) {
    if (t < ntl) {
      ushort4 x = *(const ushort4*)(base + (size_t)t * 65536);
      int c0 = t * 256 + lane * 4;
      v[t][0] = (c0 + 0 <= q) ? bf2f(x.x) : -INFINITY;
      v[t][1] = (c0 + 1 <= q) ? bf2f(x.y) : -INFINITY;
      v[t][2] = (c0 + 2 <= q) ? bf2f(x.z) : -INFINITY;
      v[t][3] = (c0 + 3 <= q) ? bf2f(x.w) : -INFINITY;
    } else {
      v[t][0] = v[t][1] = v[t][2] = v[t][3] = -INFINITY;
    }
  }
  float m = -INFINITY;
#pragma unroll
  for (int t = 0; t < 8; ++t)
#pragma unroll
    for (int jj = 0; jj < 4; ++jj) m = fmaxf(m, v[t][jj]);
  for (int off = 32; off; off >>= 1) m = fmaxf(m, __shfl_xor(m, off));
  float s = 0.f;
#pragma unroll
  for (int t = 0; t < 8; ++t)
#pragma unroll
    for (int jj = 0; jj < 4; ++jj) { v[t][jj] = __expf(v[t][jj] - m); s += v[t][jj]; }
  for (int off = 32; off; off >>= 1) s += __shfl_xor(s, off);
  const float inv = 1.f / s;
#pragma unroll
  for (int t = 0; t < 8; ++t)
    if (t < ntl) {
      ushort4 o;
      o.x = f2bf(v[t][0] * inv); o.y = f2bf(v[t][1] * inv);
      o.z = f2bf(v[t][2] * inv); o.w = f2bf(v[t][3] * inv);
      *(ushort4*)(base + (size_t)t * 65536) = o;
    }
}

// ---------- pass 3: O = P V from packed tiles, truncated K ----------
__global__ __launch_bounds__(512, 2) void k_pv(const unsigned short* __restrict__ P,
                                               const unsigned short* __restrict__ Vt,
                                               float* __restrict__ out) {
  __shared__ char smem[131072];
  const int mtr = 7 - blockIdx.x;   // long rows first
  const int nt = blockIdx.y, b = blockIdx.z;
  const int nkt = (mtr + 1) * 4;
  const char* Pb = (const char*)P + (((size_t)(b * 36 + (mtr * (mtr + 1)) / 2)) << 17);
  int rowl, slot; lane_src(0, rowl, slot);
  const char* Asrc = Pb + (size_t)rowl * 512 + slot * 16;
  const char* Bsrc = (const char*)Vt + ((size_t)(b * 1024 + nt * 256 + rowl)) * 4096 + slot * 16;
  f32x4 acc[8][4];
#pragma unroll
  for (int a = 0; a < 8; ++a)
#pragma unroll
    for (int c = 0; c < 4; ++c) acc[a][c] = (f32x4){0.f, 0.f, 0.f, 0.f};
  core256(Asrc, Bsrc, (size_t)128 * 512, (size_t)128 * 4096,
          OffTri{}, OffLinear{}, nkt, smem, acc);
  const int tid = threadIdx.x, w = tid >> 6, lane = tid & 63;
  const int lr = lane & 15, lq = lane >> 4;
  const int wm = (w >> 2) * 128, wn = (w & 3) * 64;
#pragma unroll
  for (int fr = 0; fr < 8; ++fr)
#pragma unroll
    for (int fc = 0; fc < 4; ++fc)
#pragma unroll
      for (int i2 = 0; i2 < 4; ++i2) {
        int orow = mtr * 256 + wm + fr * 16 + lq * 4 + i2;
        int col = nt * 256 + wn + fc * 16 + lr;
        out[((size_t)b * 2048 + orow) * 1024 + col] = acc[fr][fc][i2];
      }
}

extern "C" void kernel_launch(void* const* d_in, const int* in_sizes, int n_in,
                              void* d_out, int out_size, void* d_ws, size_t ws_size,
                              hipStream_t stream) {
  const float* X  = (const float*)d_in[0];
  const float* W0p = (const float*)d_in[1];
  const float* W1p = (const float*)d_in[2];
  const float* W2p = (const float*)d_in[3];
  float* out = (float*)d_out;
  char* ws = (char*)d_ws;
  unsigned short* Xb = (unsigned short*)ws;                       // 16 MB
  unsigned short* Wt = (unsigned short*)(ws + (size_t)16777216);  // 6 MB
  unsigned short* Qm = (unsigned short*)(ws + (size_t)23068672);  // 16 MB
  unsigned short* Km = (unsigned short*)(ws + (size_t)39845888);  // 16 MB
  unsigned short* Vt = (unsigned short*)(ws + (size_t)56623104);  // 16 MB
  unsigned short* Sb = (unsigned short*)ws;   // packed-tri S, 18MB (dead Xb/Wt)
  (void)in_sizes; (void)n_in; (void)out_size; (void)ws_size;

  hipLaunchKernelGGL(k_cvtX, dim3(4096), dim3(256), 0, stream, X, Xb);
  hipLaunchKernelGGL(k_cvtW, dim3(16, 16, 3), dim3(256), 0, stream, W0p, W1p, W2p, Wt);
  hipLaunchKernelGGL(k_qkv, dim3(32, 12), dim3(512), 0, stream, Xb, Wt, Qm, Km, Vt);
  hipLaunchKernelGGL(k_sg, dim3(36, 4), dim3(512), 0, stream, Qm, Km, Sb);
  hipLaunchKernelGGL(k_softmax, dim3(2048), dim3(256), 0, stream, Sb);
  hipLaunchKernelGGL(k_pv, dim3(8, 4, 4), dim3(512), 0, stream, Sb, Vt, out);
}